// Round 8
// baseline (49978.238 us; speedup 1.0000x reference)
//
#include <hip/hip_runtime.h>

#define BB   256
#define LAT  256
#define CND  64
#define HID  1024
#define OUTD 128
#define TLEN 512
#define GIN  192
#define G4   4096

typedef _Float16 f16x8 __attribute__((ext_vector_type(8)));
typedef float    f32x4 __attribute__((ext_vector_type(4)));

#define LOSCALE 2048.0f
#define LOINV   (1.0f / 2048.0f)

#define MFMA16(A,B,C) __builtin_amdgcn_mfma_f32_16x16x32_f16((A),(B),(C),0,0,0)

__device__ __forceinline__ float fsig(float x) {
  return 1.0f / (1.0f + exp2f(-1.4426950408889634f * x));
}
__device__ __forceinline__ float ftanh_(float x) {
  return 2.0f / (1.0f + exp2f(2.8853900817779268f * (-x))) - 1.0f;
}

// ---- device-coherent (MALL) access: per-instruction bypass, no cache-wide ops ----
__device__ __forceinline__ f16x8 ldg_sc_h8(const void* p) {
  f16x8 v;
  asm volatile("global_load_dwordx4 %0, %1, off sc0 sc1" : "=v"(v) : "v"(p));
  return v;
}
__device__ __forceinline__ void stg_sc_h(void* p, _Float16 v) {
  unsigned u = (unsigned)__builtin_bit_cast(unsigned short, v);
  asm volatile("global_store_short %0, %1, off sc0 sc1" :: "v"(p), "v"(u) : "memory");
}
__device__ __forceinline__ void stg_sc_f32(void* p, float v) {
  asm volatile("global_store_dword %0, %1, off sc0 sc1" :: "v"(p), "v"(v) : "memory");
}

template<int N> __device__ __forceinline__ void waitvm() {
  if constexpr (N == 8) asm volatile("s_waitcnt vmcnt(8)" ::: "memory");
  else                  asm volatile("s_waitcnt vmcnt(0)" ::: "memory");
  __builtin_amdgcn_sched_barrier(0);
}

// ---------------- prep kernels ----------------

__global__ void prep_init(const float* __restrict__ lat,
                          const float* __restrict__ Wh, const float* __restrict__ bh,
                          const float* __restrict__ Wc, const float* __restrict__ bc,
                          const float* __restrict__ Ws, const float* __restrict__ bs,
                          float* __restrict__ h0, _Float16* __restrict__ hH, _Float16* __restrict__ hL,
                          float* __restrict__ c0, float* __restrict__ x0)
{
  __shared__ float lat_s[8][LAT];
  int tid = threadIdx.x;
  int b0 = blockIdx.y * 8;
  for (int bb = 0; bb < 8; ++bb)
    lat_s[bb][tid] = lat[(size_t)(b0 + bb) * LAT + tid];
  __syncthreads();
  int col = blockIdx.x * 256 + tid;
  if (col >= 2 * HID + OUTD) return;
  const float* wr; float bias; int kind; int cc;
  if (col < HID)            { cc = col;           wr = Wh + (size_t)cc * LAT; bias = bh[cc]; kind = 0; }
  else if (col < 2 * HID)   { cc = col - HID;     wr = Wc + (size_t)cc * LAT; bias = bc[cc]; kind = 1; }
  else                      { cc = col - 2 * HID; wr = Ws + (size_t)cc * LAT; bias = bs[cc]; kind = 2; }
  float acc[8];
#pragma unroll
  for (int bb = 0; bb < 8; ++bb) acc[bb] = bias;
  for (int k = 0; k < LAT; ++k) {
    float wv = wr[k];
#pragma unroll
    for (int bb = 0; bb < 8; ++bb) acc[bb] += lat_s[bb][k] * wv;
  }
  for (int bb = 0; bb < 8; ++bb) {
    int b = b0 + bb;
    if (kind == 0) {
      float v = acc[bb];
      h0[(size_t)b*HID + cc] = v;
      _Float16 hi = (_Float16)v;
      hH[(size_t)b*HID + cc] = hi;
      hL[(size_t)b*HID + cc] = (_Float16)((v - (float)hi) * LOSCALE);
    }
    else if (kind == 1) { c0[(size_t)b*HID + cc] = acc[bb]; }
    else                { x0[(size_t)b*OUTD + cc] = acc[bb]; }
  }
}

__global__ void prep_d(const float* __restrict__ h0, const float* __restrict__ Wout,
                       const float* __restrict__ bout, const float* __restrict__ x0,
                       float* __restrict__ d)
{
  int t = blockIdx.x * 256 + threadIdx.x;
  int b = t >> 7, o = t & 127;
  const float* wr = Wout + (size_t)o * HID;
  const float* hr = h0 + (size_t)b * HID;
  float acc = bout[o];
  for (int k = 0; k < HID; ++k) acc += hr[k] * wr[k];
  d[t] = x0[t] - acc;
}

// Weff -> fragment-major layout Wp[g][nt][kc][l15][lh*8+e]; every wave-load is 1KB contiguous
__global__ void prep_weff(const float* __restrict__ Whh, const float* __restrict__ Wih,
                          const float* __restrict__ Wout,
                          _Float16* __restrict__ WpH, _Float16* __restrict__ WpL)
{
  int k = blockIdx.x * 256 + threadIdx.x;   // 0..1023
  int n0 = blockIdx.y * 16;
  float acc[16];
#pragma unroll
  for (int nn = 0; nn < 16; ++nn) acc[nn] = Whh[(size_t)(n0 + nn) * HID + k];
  for (int jj = 0; jj < OUTD; ++jj) {
    float wo = Wout[(size_t)jj * HID + k];
#pragma unroll
    for (int nn = 0; nn < 16; ++nn) acc[nn] += Wih[(size_t)(n0 + nn) * GIN + jj] * wo;
  }
  int kc = k >> 5, lh = (k >> 3) & 3, e = k & 7;
#pragma unroll
  for (int nn = 0; nn < 16; ++nn) {
    int n = n0 + nn;
    int g = n >> 10, rem = n & 1023;
    int ntq = rem >> 4, lq = rem & 15;
    size_t idx = (size_t)g * 1048576 + (size_t)ntq * 16384 + kc * 512 + lq * 32 + lh * 8 + e;
    float wv = acc[nn];
    _Float16 hi = (_Float16)wv;
    WpH[idx] = hi;
    WpL[idx] = (_Float16)((wv - (float)hi) * LOSCALE);
  }
}

__global__ void prep_wob(const float* __restrict__ Wout, _Float16* __restrict__ Wyp) {
  int t = blockIdx.x * 256 + threadIdx.x;   // 0..131071
  int o = t >> 10, k = t & 1023;
  int ntq = o >> 4, lq = o & 15;
  int kc = k >> 5, lh = (k >> 3) & 3, e = k & 7;
  size_t idx = (size_t)ntq * 16384 + kc * 512 + lq * 32 + lh * 8 + e;
  Wyp[idx] = (_Float16)Wout[t];
}

__global__ void prep_bias(const float* __restrict__ cond, const float* __restrict__ Wih,
                          const float* __restrict__ bih, const float* __restrict__ bhh,
                          const float* __restrict__ bout, const float* __restrict__ d,
                          float* __restrict__ biasR, float* __restrict__ biasS)
{
  __shared__ float cond_s[8][CND];
  __shared__ float d_s[8][OUTD];
  int tid = threadIdx.x;
  int b0 = blockIdx.y * 8;
  for (int qq = 0; qq < 2; ++qq) {
    int idx = qq * 256 + tid;
    cond_s[idx >> 6][idx & 63] = cond[(size_t)(b0 + (idx >> 6)) * CND + (idx & 63)];
  }
  for (int qq = 0; qq < 4; ++qq) {
    int idx = qq * 256 + tid;
    d_s[idx >> 7][idx & 127] = d[(size_t)(b0 + (idx >> 7)) * OUTD + (idx & 127)];
  }
  __syncthreads();
  int n = blockIdx.x * 256 + tid;
  const float* wi = Wih + (size_t)n * GIN;
  float base = bih[n] + bhh[n];
  float aR[8], aS[8];
#pragma unroll
  for (int bb = 0; bb < 8; ++bb) { aR[bb] = 0.f; aS[bb] = 0.f; }
  for (int cc = 0; cc < CND; ++cc) {
    float wv = wi[OUTD + cc];
#pragma unroll
    for (int bb = 0; bb < 8; ++bb) aR[bb] += cond_s[bb][cc] * wv;
  }
  for (int o = 0; o < OUTD; ++o) {
    float wv = wi[o];
    float bo = bout[o];
#pragma unroll
    for (int bb = 0; bb < 8; ++bb) { aR[bb] += bo * wv; aS[bb] += d_s[bb][o] * wv; }
  }
  for (int bb = 0; bb < 8; ++bb) {
    size_t idx = (size_t)(b0 + bb) * G4 + n;
    biasR[idx] = base + aR[bb];
    biasS[idx] = base + aR[bb] + aS[bb];
  }
}

// ---------------- main persistent kernel ----------------
// 256 wgs = 4 mt x 64 nt; 4 waves each (w = 16-batch-row slice). NO LDS, NO __syncthreads.
// Each wave: direct per-lane fragment loads (sc bypass), per-wave flag publish,
// consumers poll only their own (mt,w) row-group's 64 producer flags.

__global__ __launch_bounds__(256, 1)
void lstm_main(_Float16* hH, _Float16* hL, const float* __restrict__ c0g,
               const float* __restrict__ biasR, const float* __restrict__ biasS,
               const _Float16* __restrict__ WpH, const _Float16* __restrict__ WpL,
               const _Float16* __restrict__ Wyp, const float* __restrict__ bout,
               const int* __restrict__ len, float* __restrict__ out, unsigned* flags)
{
  const int wg = blockIdx.x;
  const int xcd = wg & 7, slot = wg >> 3;
  const int q = slot >> 2, mt = slot & 3;
  const int nt = q * 8 + xcd;                 // W-slice (2MB/XCD) stays in this XCD's L2
  const int tid = threadIdx.x;
  const int w = tid >> 6, lane = tid & 63;
  const int l15 = lane & 15, lh = lane >> 4;
  const int rowA = w * 16 + l15;
  const int bD0 = mt * 64 + w * 16 + lh * 4;
  const int j = nt * 16 + l15;
  const bool doy = (nt < 8);
  const int oy = doy ? nt * 16 + l15 : 0;
  const float bo = doy ? bout[oy] : 0.0f;

  const _Float16* wpH[4]; const _Float16* wpL[4];
#pragma unroll
  for (int g = 0; g < 4; ++g) {
    size_t b = (size_t)g * 1048576 + (size_t)nt * 16384 + l15 * 32 + lh * 8;
    wpH[g] = WpH + b;
    wpL[g] = WpL + b;
  }
  const _Float16* wyp = Wyp + (size_t)nt * 16384 + l15 * 32 + lh * 8;

  float c[4]; int mylen[4]; float biasRv[16];
#pragma unroll
  for (int r = 0; r < 4; ++r) {
    c[r] = c0g[(size_t)(bD0 + r) * HID + j];
    mylen[r] = len[bD0 + r];
#pragma unroll
    for (int g = 0; g < 4; ++g)
      biasRv[r * 4 + g] = biasR[(size_t)(bD0 + r) * G4 + g * HID + nt * 16 + l15];
  }

  const size_t haoff = (size_t)(mt * 64 + rowA) * HID + lh * 8;   // A-fragment element offset
  _Float16* hsH[4]; _Float16* hsL[4];
#pragma unroll
  for (int r = 0; r < 4; ++r) {
    size_t so = (size_t)(bD0 + r) * HID + j;
    hsH[r] = hH + so;
    hsL[r] = hL + so;
  }

  unsigned* const myflag = flags + ((size_t)((mt * 4 + w) * 64 + nt)) * 64;   // 256B lines
  const unsigned* const flrow = flags + ((size_t)((mt * 4 + w) * 64)) * 64;

  f32x4 accM[4], accC[4], accyM, accyC;
  f16x8 pf[2][8];   // [buf][kc*2 + {H,L}]

  for (int t = 0; t < TLEN; ++t) {
    const size_t pin  = (size_t)(t & 1) * (BB * HID);
    const size_t pout = (size_t)((t + 1) & 1) * (BB * HID);

    // ---- wait for my row-group's producers (64 flags, one per lane) ----
    if (t > 0) {
      const unsigned* fl = flrow + (size_t)lane * 64;
      long guard = 0;
      for (;;) {
        unsigned v = __hip_atomic_load(fl, __ATOMIC_RELAXED, __HIP_MEMORY_SCOPE_AGENT);
        if (__ballot(v >= (unsigned)t) == ~0ull) break;
        if (++guard > 2000000L) break;   // tripwire: fail visibly, don't hang
        __builtin_amdgcn_s_sleep(1);
      }
      __builtin_amdgcn_sched_barrier(0);
    }

    auto issue = [&](int buf, int cc) {
      const _Float16* bH = hH + pin + haoff + cc * 128;
      const _Float16* bL = hL + pin + haoff + cc * 128;
#pragma unroll
      for (int kc = 0; kc < 4; ++kc) {
        pf[buf][kc * 2]     = ldg_sc_h8(bH + kc * 32);
        pf[buf][kc * 2 + 1] = ldg_sc_h8(bL + kc * 32);
      }
    };
    auto comp = [&](int buf, int cc) {
#pragma unroll
      for (int kc = 0; kc < 4; ++kc) {
        f16x8 aH = pf[buf][kc * 2];
        f16x8 aL = pf[buf][kc * 2 + 1];
        const int wo = (cc * 4 + kc) * 512;
#pragma unroll
        for (int g = 0; g < 4; ++g) {
          f16x8 wHv = *(const f16x8*)(wpH[g] + wo);
          f16x8 wLv = *(const f16x8*)(wpL[g] + wo);
          accM[g] = MFMA16(aH, wHv, accM[g]);
          accC[g] = MFMA16(aL, wHv, accC[g]);
          accC[g] = MFMA16(aH, wLv, accC[g]);
        }
        if (doy) {
          f16x8 wyv = *(const f16x8*)(wyp + wo);
          accyM = MFMA16(aH, wyv, accyM);
          accyC = MFMA16(aL, wyv, accyC);
        }
      }
    };

    // accumulator init
#pragma unroll
    for (int r = 0; r < 4; ++r) {
#pragma unroll
      for (int g = 0; g < 4; ++g) { accM[g][r] = biasRv[r * 4 + g]; accC[g][r] = 0.f; }
      accyM[r] = bo; accyC[r] = 0.f;
    }
    if (t == 0) {
#pragma unroll
      for (int r = 0; r < 4; ++r)
#pragma unroll
        for (int g = 0; g < 4; ++g)
          accM[g][r] = biasS[(size_t)(bD0 + r) * G4 + g * HID + nt * 16 + l15];
    }

    issue(0, 0); issue(1, 1);
    waitvm<8>(); comp(0, 0); issue(0, 2);
    waitvm<8>(); comp(1, 1); issue(1, 3);
    waitvm<8>(); comp(0, 2); issue(0, 4);
    waitvm<8>(); comp(1, 3); issue(1, 5);
    waitvm<8>(); comp(0, 4); issue(0, 6);
    waitvm<8>(); comp(1, 5); issue(1, 7);
    waitvm<8>(); comp(0, 6);
    waitvm<0>(); comp(1, 7);

    // LSTM cell (fp32), h_{t+1} hi/lo stores (bypass)
#pragma unroll
    for (int r = 0; r < 4; ++r) {
      float zi = accM[0][r] + accC[0][r] * LOINV;
      float zf = accM[1][r] + accC[1][r] * LOINV;
      float zg = accM[2][r] + accC[2][r] * LOINV;
      float zo = accM[3][r] + accC[3][r] * LOINV;
      float ig = fsig(zi);
      float fg = fsig(zf);
      float gg = ftanh_(zg);
      float og = fsig(zo);
      float cn = fg * c[r] + ig * gg;
      c[r] = cn;
      float hn = og * ftanh_(cn);
      _Float16 hi = (_Float16)hn;
      _Float16 lo = (_Float16)((hn - (float)hi) * LOSCALE);
      stg_sc_h(hsH[r] + pout, hi);
      stg_sc_h(hsL[r] + pout, lo);
    }
    if (doy && t > 0) {
      int tb = t - 1;
#pragma unroll
      for (int r = 0; r < 4; ++r) {
        float v = (tb < mylen[r]) ? (accyM[r] + accyC[r] * LOINV) : 0.0f;
        stg_sc_f32(out + ((size_t)(bD0 + r) * TLEN + tb) * OUTD + oy, v);
      }
    }

    // publish: stores ACKed at MALL, then monotone per-wave flag
    asm volatile("s_waitcnt vmcnt(0)" ::: "memory");
    if (lane == 0)
      __hip_atomic_store(myflag, (unsigned)(t + 1), __ATOMIC_RELAXED, __HIP_MEMORY_SCOPE_AGENT);
  }

  // epilogue: y_{511} = Wout*h_512 + bout (h_512 in parity-0 buffers)
  if (doy) {
    {
      const unsigned* fl = flrow + (size_t)lane * 64;
      long guard = 0;
      for (;;) {
        unsigned v = __hip_atomic_load(fl, __ATOMIC_RELAXED, __HIP_MEMORY_SCOPE_AGENT);
        if (__ballot(v >= (unsigned)TLEN) == ~0ull) break;
        if (++guard > 2000000L) break;
        __builtin_amdgcn_s_sleep(1);
      }
      __builtin_amdgcn_sched_barrier(0);
    }
    f32x4 aM, aC;
#pragma unroll
    for (int r = 0; r < 4; ++r) { aM[r] = bo; aC[r] = 0.f; }
    for (int cc = 0; cc < 8; ++cc) {
      f16x8 e[8];
#pragma unroll
      for (int kc = 0; kc < 4; ++kc) {
        e[kc * 2]     = ldg_sc_h8(hH + haoff + cc * 128 + kc * 32);
        e[kc * 2 + 1] = ldg_sc_h8(hL + haoff + cc * 128 + kc * 32);
      }
      waitvm<0>();
#pragma unroll
      for (int kc = 0; kc < 4; ++kc) {
        const int wo = (cc * 4 + kc) * 512;
        f16x8 wyv = *(const f16x8*)(wyp + wo);
        aM = MFMA16(e[kc * 2], wyv, aM);
        aC = MFMA16(e[kc * 2 + 1], wyv, aC);
      }
    }
#pragma unroll
    for (int r = 0; r < 4; ++r) {
      float v = ((TLEN - 1) < mylen[r]) ? (aM[r] + aC[r] * LOINV) : 0.0f;
      stg_sc_f32(out + ((size_t)(bD0 + r) * TLEN + (TLEN - 1)) * OUTD + oy, v);
    }
  }
}

// ---------------- host ----------------

extern "C" void kernel_launch(void* const* d_in, const int* in_sizes, int n_in,
                              void* d_out, int out_size, void* d_ws, size_t ws_size,
                              hipStream_t stream)
{
  const float* lat  = (const float*)d_in[0];
  const float* cond = (const float*)d_in[1];
  const int*   len  = (const int*)d_in[2];
  const float* Wh   = (const float*)d_in[3];
  const float* bh   = (const float*)d_in[4];
  const float* Wc   = (const float*)d_in[5];
  const float* bc   = (const float*)d_in[6];
  const float* Ws   = (const float*)d_in[7];
  const float* bs   = (const float*)d_in[8];
  const float* Wih  = (const float*)d_in[9];
  const float* Whh  = (const float*)d_in[10];
  const float* bih  = (const float*)d_in[11];
  const float* bhh  = (const float*)d_in[12];
  const float* Wout = (const float*)d_in[13];
  const float* bout = (const float*)d_in[14];
  float* out = (float*)d_out;

  char* ws = (char*)d_ws;
  size_t off = 0;
  auto alloc = [&](size_t bytes) -> void* {
    void* p = ws + off;
    off += (bytes + 255) & ~(size_t)255;
    return p;
  };
  _Float16* hH    = (_Float16*)alloc((size_t)2 * BB * HID * 2);
  _Float16* hL    = (_Float16*)alloc((size_t)2 * BB * HID * 2);
  float*    c0    = (float*)alloc((size_t)BB * HID * 4);
  float*    h0    = (float*)alloc((size_t)BB * HID * 4);
  float*    x0    = (float*)alloc((size_t)BB * OUTD * 4);
  float*    dxy   = (float*)alloc((size_t)BB * OUTD * 4);
  _Float16* Wyp   = (_Float16*)alloc((size_t)8 * 16384 * 2);
  _Float16* WpH   = (_Float16*)alloc((size_t)4 * 1048576 * 2);
  _Float16* WpL   = (_Float16*)alloc((size_t)4 * 1048576 * 2);
  float*    biasR = (float*)alloc((size_t)BB * G4 * 4);
  float*    biasS = (float*)alloc((size_t)BB * G4 * 4);
  unsigned* flags = (unsigned*)alloc((size_t)4 * 4 * 64 * 64 * 4);   // [mt][w][nt] 256B lines
  if (off > ws_size) return;

  hipMemsetAsync(flags, 0, (size_t)4 * 4 * 64 * 64 * 4, stream);

  prep_init<<<dim3(9, 32),   256, 0, stream>>>(lat, Wh, bh, Wc, bc, Ws, bs, h0, hH, hL, c0, x0);
  prep_weff<<<dim3(4, 256),  256, 0, stream>>>(Whh, Wih, Wout, WpH, WpL);
  prep_wob <<<dim3(512),     256, 0, stream>>>(Wout, Wyp);
  prep_d   <<<dim3(128),     256, 0, stream>>>(h0, Wout, bout, x0, dxy);
  prep_bias<<<dim3(16, 32),  256, 0, stream>>>(cond, Wih, bih, bhh, bout, dxy, biasR, biasS);
  lstm_main<<<dim3(256),     256, 0, stream>>>(hH, hL, c0, biasR, biasS, WpH, WpL, Wyp, bout, len, out, flags);
}

// Round 9
// 19337.506 us; speedup vs baseline: 2.5845x; 2.5845x over previous
//
#include <hip/hip_runtime.h>

#define BB   256
#define LAT  256
#define CND  64
#define HID  1024
#define OUTD 128
#define TLEN 512
#define GIN  192
#define G4   4096

typedef _Float16 f16x8 __attribute__((ext_vector_type(8)));
typedef float    f32x4 __attribute__((ext_vector_type(4)));

#define LOSCALE 2048.0f
#define LOINV   (1.0f / 2048.0f)

#define MFMA16(A,B,C) __builtin_amdgcn_mfma_f32_16x16x32_f16((A),(B),(C),0,0,0)

__device__ __forceinline__ float fsig(float x) {
  return 1.0f / (1.0f + exp2f(-1.4426950408889634f * x));
}
__device__ __forceinline__ float ftanh_(float x) {
  return 2.0f / (1.0f + exp2f(2.8853900817779268f * (-x))) - 1.0f;
}

// ---- device-coherent (MALL) access: per-instruction bypass, no cache-wide ops ----
__device__ __forceinline__ f16x8 ldg_sc_h8(const void* p) {
  f16x8 v;
  asm volatile("global_load_dwordx4 %0, %1, off sc0 sc1" : "=v"(v) : "v"(p));
  return v;
}
__device__ __forceinline__ void stg_sc_h(void* p, _Float16 v) {
  unsigned u = (unsigned)__builtin_bit_cast(unsigned short, v);
  asm volatile("global_store_short %0, %1, off sc0 sc1" :: "v"(p), "v"(u) : "memory");
}
__device__ __forceinline__ void stg_sc_f32(void* p, float v) {
  asm volatile("global_store_dword %0, %1, off sc0 sc1" :: "v"(p), "v"(v) : "memory");
}

template<int N> __device__ __forceinline__ void waitvm() {
  if constexpr (N == 12)     asm volatile("s_waitcnt vmcnt(12)" ::: "memory");
  else if constexpr (N == 8) asm volatile("s_waitcnt vmcnt(8)"  ::: "memory");
  else if constexpr (N == 4) asm volatile("s_waitcnt vmcnt(4)"  ::: "memory");
  else                       asm volatile("s_waitcnt vmcnt(0)"  ::: "memory");
  __builtin_amdgcn_sched_barrier(0);
}
#define LDSBAR() { asm volatile("s_waitcnt lgkmcnt(0)" ::: "memory"); \
                   __builtin_amdgcn_s_barrier(); \
                   __builtin_amdgcn_sched_barrier(0); }

// ---------------- prep kernels ----------------

__global__ void prep_init(const float* __restrict__ lat,
                          const float* __restrict__ Wh, const float* __restrict__ bh,
                          const float* __restrict__ Wc, const float* __restrict__ bc,
                          const float* __restrict__ Ws, const float* __restrict__ bs,
                          float* __restrict__ h0, _Float16* __restrict__ hF,
                          float* __restrict__ c0, float* __restrict__ x0)
{
  __shared__ float lat_s[8][LAT];
  int tid = threadIdx.x;
  int b0 = blockIdx.y * 8;
  for (int bb = 0; bb < 8; ++bb)
    lat_s[bb][tid] = lat[(size_t)(b0 + bb) * LAT + tid];
  __syncthreads();
  int col = blockIdx.x * 256 + tid;
  if (col >= 2 * HID + OUTD) return;
  const float* wr; float bias; int kind; int cc;
  if (col < HID)            { cc = col;           wr = Wh + (size_t)cc * LAT; bias = bh[cc]; kind = 0; }
  else if (col < 2 * HID)   { cc = col - HID;     wr = Wc + (size_t)cc * LAT; bias = bc[cc]; kind = 1; }
  else                      { cc = col - 2 * HID; wr = Ws + (size_t)cc * LAT; bias = bs[cc]; kind = 2; }
  float acc[8];
#pragma unroll
  for (int bb = 0; bb < 8; ++bb) acc[bb] = bias;
  for (int k = 0; k < LAT; ++k) {
    float wv = wr[k];
#pragma unroll
    for (int bb = 0; bb < 8; ++bb) acc[bb] += lat_s[bb][k] * wv;
  }
  for (int bb = 0; bb < 8; ++bb) {
    int b = b0 + bb;
    if (kind == 0) {
      float v = acc[bb];
      h0[(size_t)b*HID + cc] = v;
      hF[(size_t)b*HID + cc] = (_Float16)v;
    }
    else if (kind == 1) { c0[(size_t)b*HID + cc] = acc[bb]; }
    else                { x0[(size_t)b*OUTD + cc] = acc[bb]; }
  }
}

__global__ void prep_d(const float* __restrict__ h0, const float* __restrict__ Wout,
                       const float* __restrict__ bout, const float* __restrict__ x0,
                       float* __restrict__ d)
{
  int t = blockIdx.x * 256 + threadIdx.x;
  int b = t >> 7, o = t & 127;
  const float* wr = Wout + (size_t)o * HID;
  const float* hr = h0 + (size_t)b * HID;
  float acc = bout[o];
  for (int k = 0; k < HID; ++k) acc += hr[k] * wr[k];
  d[t] = x0[t] - acc;
}

__global__ void prep_weff(const float* __restrict__ Whh, const float* __restrict__ Wih,
                          const float* __restrict__ Wout,
                          _Float16* __restrict__ WeffH, _Float16* __restrict__ WeffL)
{
  int k = blockIdx.x * 256 + threadIdx.x;
  int n0 = blockIdx.y * 16;
  float acc[16];
#pragma unroll
  for (int nn = 0; nn < 16; ++nn) acc[nn] = Whh[(size_t)(n0 + nn) * HID + k];
  for (int j = 0; j < OUTD; ++j) {
    float wo = Wout[(size_t)j * HID + k];
#pragma unroll
    for (int nn = 0; nn < 16; ++nn) acc[nn] += Wih[(size_t)(n0 + nn) * GIN + j] * wo;
  }
#pragma unroll
  for (int nn = 0; nn < 16; ++nn) {
    size_t idx = (size_t)(n0 + nn) * HID + k;
    float wv = acc[nn];
    _Float16 hi = (_Float16)wv;
    WeffH[idx] = hi;
    WeffL[idx] = (_Float16)((wv - (float)hi) * LOSCALE);
  }
}

__global__ void prep_wob(const float* __restrict__ Wout, _Float16* __restrict__ Wob) {
  int t = blockIdx.x * 256 + threadIdx.x;
  Wob[t] = (_Float16)Wout[t];
}

__global__ void prep_bias(const float* __restrict__ cond, const float* __restrict__ Wih,
                          const float* __restrict__ bih, const float* __restrict__ bhh,
                          const float* __restrict__ bout, const float* __restrict__ d,
                          float* __restrict__ biasR, float* __restrict__ biasS)
{
  __shared__ float cond_s[8][CND];
  __shared__ float d_s[8][OUTD];
  int tid = threadIdx.x;
  int b0 = blockIdx.y * 8;
  for (int qq = 0; qq < 2; ++qq) {
    int idx = qq * 256 + tid;
    cond_s[idx >> 6][idx & 63] = cond[(size_t)(b0 + (idx >> 6)) * CND + (idx & 63)];
  }
  for (int qq = 0; qq < 4; ++qq) {
    int idx = qq * 256 + tid;
    d_s[idx >> 7][idx & 127] = d[(size_t)(b0 + (idx >> 7)) * OUTD + (idx & 127)];
  }
  __syncthreads();
  int n = blockIdx.x * 256 + tid;
  const float* wi = Wih + (size_t)n * GIN;
  float base = bih[n] + bhh[n];
  float aR[8], aS[8];
#pragma unroll
  for (int bb = 0; bb < 8; ++bb) { aR[bb] = 0.f; aS[bb] = 0.f; }
  for (int c = 0; c < CND; ++c) {
    float wv = wi[OUTD + c];
#pragma unroll
    for (int bb = 0; bb < 8; ++bb) aR[bb] += cond_s[bb][c] * wv;
  }
  for (int o = 0; o < OUTD; ++o) {
    float wv = wi[o];
    float bo = bout[o];
#pragma unroll
    for (int bb = 0; bb < 8; ++bb) { aR[bb] += bo * wv; aS[bb] += d_s[bb][o] * wv; }
  }
  for (int bb = 0; bb < 8; ++bb) {
    size_t idx = (size_t)(b0 + bb) * G4 + n;
    biasR[idx] = base + aR[bb];
    biasS[idx] = base + aR[bb] + aS[bb];
  }
}

// ---------------- main persistent kernel ----------------
// r4 structure (best measured), h as single f16 plane (bypass stream halved).
// Grid: 256 wgs = 4 mt (64-batch tiles) x 64 nt (16 gate/h cols). Per-mt barrier.

__global__ __launch_bounds__(256, 1)
void lstm_main(_Float16* hF, const float* __restrict__ c0g,
               const float* __restrict__ biasR, const float* __restrict__ biasS,
               const _Float16* __restrict__ WeffH, const _Float16* __restrict__ WeffL,
               const _Float16* __restrict__ Wob, const float* __restrict__ bout,
               const int* __restrict__ len, float* __restrict__ out, unsigned* bar)
{
  __shared__ __align__(16) char lds[34816];   // 2 bufs x 17408 (64 rows x 272B)
  const int wg = blockIdx.x;
  const int xcd = wg & 7, slot = wg >> 3;
  const int q = slot >> 2, mt = slot & 3;
  const int nt = q * 8 + xcd;                 // W-slice stays in this XCD's L2
  const int tid = threadIdx.x;
  const int w = tid >> 6, lane = tid & 63;
  const int l15 = lane & 15, lh = lane >> 4;
  const int rowA = w * 16 + l15;
  const int bD0 = mt * 64 + w * 16 + lh * 4;
  const int j = nt * 16 + l15;
  const bool doy = (nt < 8);
  const int oy = doy ? nt * 16 + l15 : 0;
  const float bo = doy ? bout[oy] : 0.0f;

  // weight base pointers (cached loads; L2-resident, never invalidated)
  const char* wbH[4]; const char* wbL[4];
#pragma unroll
  for (int g = 0; g < 4; ++g) {
    size_t r0 = ((size_t)(g * HID + nt * 16 + l15)) * HID + lh * 8;
    wbH[g] = (const char*)(WeffH + r0);
    wbL[g] = (const char*)(WeffL + r0);
  }
  const char* wbY = (const char*)(Wob + (size_t)oy * HID + lh * 8);

  float c[4]; int mylen[4]; float biasRv[16];
#pragma unroll
  for (int r = 0; r < 4; ++r) {
    c[r] = c0g[(size_t)(bD0 + r) * HID + j];
    mylen[r] = len[bD0 + r];
    size_t bi = (size_t)(bD0 + r) * G4 + nt * 16 + l15;
#pragma unroll
    for (int g = 0; g < 4; ++g) biasRv[r * 4 + g] = biasR[bi + (size_t)g * HID];
  }

  // staging-slot addressing: slot s = i*256+tid -> row s>>4 (0..63), 16B-quad s&15
  const _Float16* cb0[4];
  int rc8[4];
#pragma unroll
  for (int i = 0; i < 4; ++i) {
    int s = i * 256 + tid;
    int r = s >> 4, cc = s & 15;
    cb0[i] = hF + ((size_t)(mt * 64 + r) * HID + cc * 8);
    rc8[i] = r * 272 + cc * 16;
  }
  const int rdoff = rowA * 272 + lh * 16;
  _Float16* hb0[4];
#pragma unroll
  for (int r = 0; r < 4; ++r) hb0[r] = hF + ((size_t)(bD0 + r) * HID + j);

  unsigned* const myarr = bar + (size_t)(mt * 8 + xcd) * 64;   // 256B-spaced lines

  f32x4 accM[4], accC[4], accyM;
  f16x8 pfb[4][4];

  for (int t = 0; t < TLEN; ++t) {
    const size_t parin  = (size_t)(t & 1) * (BB * HID);
    const size_t parout = (size_t)((t + 1) & 1) * (BB * HID);

    auto issue = [&](int K) {
#pragma unroll
      for (int i = 0; i < 4; ++i)
        pfb[K & 3][i] = ldg_sc_h8(cb0[i] + parin + K * 128);
    };
    auto dswr = [&](int K) {
      char* Bb = lds + (K & 1) * 17408;
#pragma unroll
      for (int i = 0; i < 4; ++i)
        *(f16x8*)(Bb + rc8[i]) = pfb[K & 3][i];
    };
    auto comp = [&](int K) {
      const char* Bb = lds + (K & 1) * 17408;
#pragma unroll
      for (int kc = 0; kc < 4; ++kc) {
        f16x8 aH = *(const f16x8*)(Bb + rdoff + kc * 64);
        const int wo = K * 256 + kc * 64;
#pragma unroll
        for (int g = 0; g < 4; ++g) {
          f16x8 wH = *(const f16x8*)(wbH[g] + wo);
          f16x8 wL = *(const f16x8*)(wbL[g] + wo);
          accM[g] = MFMA16(aH, wH, accM[g]);
          accC[g] = MFMA16(aH, wL, accC[g]);
        }
        if (doy) {
          f16x8 wy = *(const f16x8*)(wbY + wo);
          accyM = MFMA16(aH, wy, accyM);
        }
      }
    };

    // prefetch 4 chunks deep (16 loads in flight)
    issue(0); issue(1); issue(2); issue(3);

    // accumulator init
#pragma unroll
    for (int r = 0; r < 4; ++r) {
#pragma unroll
      for (int g = 0; g < 4; ++g) { accM[g][r] = biasRv[r * 4 + g]; accC[g][r] = 0.f; }
      accyM[r] = bo;
    }
    if (t == 0) {
#pragma unroll
      for (int r = 0; r < 4; ++r) {
        size_t bi = (size_t)(bD0 + r) * G4 + nt * 16 + l15;
#pragma unroll
        for (int g = 0; g < 4; ++g) accM[g][r] = biasS[bi + (size_t)g * HID];
      }
    }

    waitvm<12>(); dswr(0); LDSBAR(); issue(4); comp(0);
    waitvm<12>(); dswr(1); LDSBAR(); issue(5); comp(1);
    waitvm<12>(); dswr(2); LDSBAR(); issue(6); comp(2);
    waitvm<12>(); dswr(3); LDSBAR(); issue(7); comp(3);
    waitvm<12>(); dswr(4); LDSBAR(); comp(4);
    waitvm<8>();  dswr(5); LDSBAR(); comp(5);
    waitvm<4>();  dswr(6); LDSBAR(); comp(6);
    waitvm<0>();  dswr(7); LDSBAR(); comp(7);

    // LSTM cell (fp32), f16 h_{t+1} store
#pragma unroll
    for (int r = 0; r < 4; ++r) {
      float zi = accM[0][r] + accC[0][r] * LOINV;
      float zf = accM[1][r] + accC[1][r] * LOINV;
      float zg = accM[2][r] + accC[2][r] * LOINV;
      float zo = accM[3][r] + accC[3][r] * LOINV;
      float ig = fsig(zi);
      float fg = fsig(zf);
      float gg = ftanh_(zg);
      float og = fsig(zo);
      float cn = fg * c[r] + ig * gg;
      c[r] = cn;
      float hn = og * ftanh_(cn);
      stg_sc_h(hb0[r] + parout, (_Float16)hn);
    }
    if (doy && t > 0) {
      int tb = t - 1;
#pragma unroll
      for (int r = 0; r < 4; ++r) {
        float v = (tb < mylen[r]) ? accyM[r] : 0.0f;
        stg_sc_f32(out + ((size_t)(bD0 + r) * TLEN + tb) * OUTD + oy, v);
      }
    }

    // ---- per-mt barrier: 8 spread arrival lines + wave-parallel poll ----
    asm volatile("s_waitcnt vmcnt(0)" ::: "memory");
    __syncthreads();
    if (tid < 64) {
      if (tid == 0)
        __hip_atomic_fetch_add(myarr, 1u, __ATOMIC_RELAXED, __HIP_MEMORY_SCOPE_AGENT);
      if (t < TLEN - 1 || doy) {
        unsigned tgt = 8u * (unsigned)(t + 1);
        long guard = 0;
        for (;;) {
          unsigned v = tgt;
          if (tid < 8)
            v = __hip_atomic_load(bar + (size_t)(mt * 8 + tid) * 64,
                                  __ATOMIC_RELAXED, __HIP_MEMORY_SCOPE_AGENT);
          if (__ballot(v >= tgt) == ~0ull) break;
          if (++guard > 2000000L) break;   // tripwire: fail visibly, don't hang
          __builtin_amdgcn_s_sleep(2);
        }
      }
    }
    __syncthreads();
  }

  // epilogue: y_{511} = Wout*h_512 + bout   (h_512 in parity-0 buffer)
  if (doy) {
    f32x4 aM;
#pragma unroll
    for (int r = 0; r < 4; ++r) aM[r] = bo;
    const _Float16* ebase = hF + (size_t)(mt * 64 + rowA) * HID + lh * 8;
    for (int b = 0; b < 8; ++b) {
      f16x8 e[4];
#pragma unroll
      for (int kc = 0; kc < 4; ++kc)
        e[kc] = ldg_sc_h8(ebase + b * 128 + kc * 32);
      asm volatile("s_waitcnt vmcnt(0)" ::: "memory");
      __builtin_amdgcn_sched_barrier(0);
#pragma unroll
      for (int kc = 0; kc < 4; ++kc) {
        f16x8 wy = *(const f16x8*)(wbY + b * 256 + kc * 64);
        aM = MFMA16(e[kc], wy, aM);
      }
    }
#pragma unroll
    for (int r = 0; r < 4; ++r) {
      float v = ((TLEN - 1) < mylen[r]) ? aM[r] : 0.0f;
      stg_sc_f32(out + ((size_t)(bD0 + r) * TLEN + (TLEN - 1)) * OUTD + oy, v);
    }
  }
}

// ---------------- host ----------------

extern "C" void kernel_launch(void* const* d_in, const int* in_sizes, int n_in,
                              void* d_out, int out_size, void* d_ws, size_t ws_size,
                              hipStream_t stream)
{
  const float* lat  = (const float*)d_in[0];
  const float* cond = (const float*)d_in[1];
  const int*   len  = (const int*)d_in[2];
  const float* Wh   = (const float*)d_in[3];
  const float* bh   = (const float*)d_in[4];
  const float* Wc   = (const float*)d_in[5];
  const float* bc   = (const float*)d_in[6];
  const float* Ws   = (const float*)d_in[7];
  const float* bs   = (const float*)d_in[8];
  const float* Wih  = (const float*)d_in[9];
  const float* Whh  = (const float*)d_in[10];
  const float* bih  = (const float*)d_in[11];
  const float* bhh  = (const float*)d_in[12];
  const float* Wout = (const float*)d_in[13];
  const float* bout = (const float*)d_in[14];
  float* out = (float*)d_out;

  char* ws = (char*)d_ws;
  size_t off = 0;
  auto alloc = [&](size_t bytes) -> void* {
    void* p = ws + off;
    off += (bytes + 255) & ~(size_t)255;
    return p;
  };
  _Float16* hF    = (_Float16*)alloc((size_t)2 * BB * HID * 2);   // single f16 plane
  float*    c0    = (float*)alloc((size_t)BB * HID * 4);
  float*    h0    = (float*)alloc((size_t)BB * HID * 4);
  float*    x0    = (float*)alloc((size_t)BB * OUTD * 4);
  float*    dxy   = (float*)alloc((size_t)BB * OUTD * 4);
  _Float16* Wob   = (_Float16*)alloc((size_t)OUTD * HID * 2);
  _Float16* WeffH = (_Float16*)alloc((size_t)G4 * HID * 2);
  _Float16* WeffL = (_Float16*)alloc((size_t)G4 * HID * 2);
  float*    biasR = (float*)alloc((size_t)BB * G4 * 4);
  float*    biasS = (float*)alloc((size_t)BB * G4 * 4);
  unsigned* bar   = (unsigned*)alloc(4 * 8 * 64 * 4);             // 32 lines, 256B apart
  if (off > ws_size) return;

  hipMemsetAsync(bar, 0, 4 * 8 * 64 * 4, stream);

  prep_init<<<dim3(9, 32),   256, 0, stream>>>(lat, Wh, bh, Wc, bc, Ws, bs, h0, hF, c0, x0);
  prep_weff<<<dim3(4, 256),  256, 0, stream>>>(Whh, Wih, Wout, WeffH, WeffL);
  prep_wob <<<dim3(512),     256, 0, stream>>>(Wout, Wob);
  prep_d   <<<dim3(128),     256, 0, stream>>>(h0, Wout, bout, x0, dxy);
  prep_bias<<<dim3(16, 32),  256, 0, stream>>>(cond, Wih, bih, bhh, bout, dxy, biasR, biasS);
  lstm_main<<<dim3(256),     256, 0, stream>>>(hF, c0, biasR, biasS, WeffH, WeffL, Wob, bout, len, out, bar);
}